// Round 8
// baseline (262.480 us; speedup 1.0000x reference)
//
#include <hip/hip_runtime.h>
#include <math.h>

// Problem constants (from reference): B=32, I=2048, O=32, C=16, U=32
#define B_   32
#define I_   2048
#define O_   32
#define C_   16
#define U_   32
#define NCOL   (O_ * U_)      // 1024 output columns (o,u)
#define TI     8              // i-values per block
#define NIG    (I_ / TI)      // 256 i-groups = partial slices
#define CQ     4              // column quarters -> grid = NIG*CQ = 1024 blocks
#define SLICE  (B_ * NCOL)    // 32768 floats per partial slice
#define XS     36             // x LDS stride (floats): 144 B = mult of 16 (aligned b128)
#define WT4    1024           // w tile in float4s: 8o x 16c x 8k = 16 KB

// softmax over the singleton axis of b_log is identically 1 -> routing
// iterations are no-ops. Output = squash(sum_{i,c} x[b,i,c] * w[i,o,c,u]).
//
// R8: R7's w LDS reads were 8-way bank-conflicted (o-stride 512 == 0 mod 32:
// all 8 ol-groups hit the same banks, different rows -> SQ_LDS_BANK_CONFLICT
// 2.49M). Fix: store the w tile in LDS in COMPUTE-READ ORDER (c-major,
// wbuf4[c*64 + colf4]) so compute reads are canonical stride-1 b128 (64
// lanes -> 1 KB contiguous, 2-way = free) and staging ds_writes are 2-way
// too. Transpose is free (it's just the LDS write addressing); global loads
// stay fully coalesced. Staging still via named-register round-trip with
// loads issued a full compute-phase early (R7-proven, no spill).

__global__ __launch_bounds__(256, 3) void caps_partial(const float* __restrict__ x,
                                                       const float* __restrict__ w,
                                                       float* __restrict__ ws) {
    __shared__ float4 wbuf[2][WT4];      // 32 KB double-buffered w tile (c-major)
    __shared__ float  xs[TI * C_ * XS];  // 18.4 KB; xs[(il*16+c)*36 + b]
    const int tid = threadIdx.x;         // 0..255
    const int ig  = blockIdx.x >> 2;     // i-group
    const int cq  = blockIdx.x & 3;      // column quarter (8 o's)
    const int i0  = ig * TI;

    // Stage x[:, i0:i0+TI, :] -> LDS. Global coalesced (rem lane-fast).
    // Write bank = (4*rem + b) % 32 -> 2-way per quarter-phase (free).
    for (int k = tid; k < B_ * TI * C_; k += 256) {
        int b   = k >> 7;                // / (TI*C_) == 128
        int rem = k & 127;               // il*16 + c
        xs[rem * XS + b] = x[(size_t)b * (I_ * C_) + (size_t)i0 * C_ + rem];
    }

    // w tile for il: 16 KB contiguous at w + ((i0+il)*O + cq*8)*(C*U).
    // Global f4 index g decomposes as g = ol*128 + c*8 + k ([o][c][u] layout);
    // LDS destination (c-major read order) = c*64 + ol*8 + k.
    const float4* wt0 = (const float4*)(w + ((size_t)i0 * O_ + (size_t)cq * 8) * (C_ * U_));
    const int tstride = O_ * C_ * U_ / 4;   // f4 stride between consecutive i

    int lidx[4];
#pragma unroll
    for (int j = 0; j < 4; ++j) {
        int g = tid + j * 256;
        lidx[j] = ((g >> 3) & 15) * 64 + (g >> 7) * 8 + (g & 7);
    }

    // Prologue: stage tile 0 (4 coalesced f4 loads -> transposed ds_writes).
    {
        float4 p0 = wt0[tid];
        float4 p1 = wt0[tid + 256];
        float4 p2 = wt0[tid + 512];
        float4 p3 = wt0[tid + 768];
        wbuf[0][lidx[0]] = p0;
        wbuf[0][lidx[1]] = p1;
        wbuf[0][lidx[2]] = p2;
        wbuf[0][lidx[3]] = p3;
    }
    __syncthreads();

    const int colf4 = tid & 63;          // lane id: ol*8 + k
    const int bg    = tid >> 6;          // batch group (8 batches), wave-uniform
    const float* xbase = xs + bg * 8;    // batches bg*8 .. bg*8+7

    float4 acc[8];
#pragma unroll
    for (int b = 0; b < 8; ++b) acc[b] = make_float4(0.f, 0.f, 0.f, 0.f);

    for (int il = 0; il < TI; ++il) {
        const int cur = il & 1;
        // Issue next tile's 4 global loads now; they stay in flight through
        // the ~1000-cycle compute phase (vmcnt wait sits at the ds_writes).
        float4 q0, q1, q2, q3;
        if (il + 1 < TI) {
            const float4* wn = wt0 + (size_t)(il + 1) * tstride;
            q0 = wn[tid];
            q1 = wn[tid + 256];
            q2 = wn[tid + 512];
            q3 = wn[tid + 768];
        }
        // Compute tile il. w read: stride-1 b128 across the wave (1 KB
        // contiguous -> conflict-free). x reads: wave-uniform b128 broadcasts.
        const float4* wrow = &wbuf[cur][colf4];
        const float*  xrow = xbase + il * C_ * XS;
#pragma unroll
        for (int c = 0; c < C_; ++c) {
            float4 wv = wrow[c * 64];
            float4 xa = *(const float4*)(xrow + c * XS);       // batches +0..3
            float4 xb = *(const float4*)(xrow + c * XS + 4);   // batches +4..7
            acc[0].x = fmaf(xa.x, wv.x, acc[0].x);
            acc[0].y = fmaf(xa.x, wv.y, acc[0].y);
            acc[0].z = fmaf(xa.x, wv.z, acc[0].z);
            acc[0].w = fmaf(xa.x, wv.w, acc[0].w);
            acc[1].x = fmaf(xa.y, wv.x, acc[1].x);
            acc[1].y = fmaf(xa.y, wv.y, acc[1].y);
            acc[1].z = fmaf(xa.y, wv.z, acc[1].z);
            acc[1].w = fmaf(xa.y, wv.w, acc[1].w);
            acc[2].x = fmaf(xa.z, wv.x, acc[2].x);
            acc[2].y = fmaf(xa.z, wv.y, acc[2].y);
            acc[2].z = fmaf(xa.z, wv.z, acc[2].z);
            acc[2].w = fmaf(xa.z, wv.w, acc[2].w);
            acc[3].x = fmaf(xa.w, wv.x, acc[3].x);
            acc[3].y = fmaf(xa.w, wv.y, acc[3].y);
            acc[3].z = fmaf(xa.w, wv.z, acc[3].z);
            acc[3].w = fmaf(xa.w, wv.w, acc[3].w);
            acc[4].x = fmaf(xb.x, wv.x, acc[4].x);
            acc[4].y = fmaf(xb.x, wv.y, acc[4].y);
            acc[4].z = fmaf(xb.x, wv.z, acc[4].z);
            acc[4].w = fmaf(xb.x, wv.w, acc[4].w);
            acc[5].x = fmaf(xb.y, wv.x, acc[5].x);
            acc[5].y = fmaf(xb.y, wv.y, acc[5].y);
            acc[5].z = fmaf(xb.y, wv.z, acc[5].z);
            acc[5].w = fmaf(xb.y, wv.w, acc[5].w);
            acc[6].x = fmaf(xb.z, wv.x, acc[6].x);
            acc[6].y = fmaf(xb.z, wv.y, acc[6].y);
            acc[6].z = fmaf(xb.z, wv.z, acc[6].z);
            acc[6].w = fmaf(xb.z, wv.w, acc[6].w);
            acc[7].x = fmaf(xb.w, wv.x, acc[7].x);
            acc[7].y = fmaf(xb.w, wv.y, acc[7].y);
            acc[7].z = fmaf(xb.w, wv.z, acc[7].z);
            acc[7].w = fmaf(xb.w, wv.w, acc[7].w);
        }
        // Drain the prefetch into the other buffer (vmcnt wait lands here,
        // after compute). Transposed writes: 2-way per quarter-phase (free).
        if (il + 1 < TI) {
            float4* wd = wbuf[cur ^ 1];
            wd[lidx[0]] = q0;
            wd[lidx[1]] = q1;
            wd[lidx[2]] = q2;
            wd[lidx[3]] = q3;
        }
        __syncthreads();
    }

    // ws[ig][b][col], col = cq*256 + colf4*4. Coalesced float4 stores.
    float* op = ws + (size_t)ig * SLICE + (size_t)(bg * 8) * NCOL + cq * 256 + colf4 * 4;
#pragma unroll
    for (int b = 0; b < 8; ++b)
        *(float4*)(op + (size_t)b * NCOL) = acc[b];
}

// Sum 256 partials per output element (4 threads/element over p-quarters),
// then squash over u (32 consecutive t = one (b,o) group; shuffle reduce).
__global__ __launch_bounds__(256) void caps_reduce_squash(const float* __restrict__ ws,
                                                          float* __restrict__ out) {
    __shared__ float sh[256];
    const int tid = threadIdx.x;
    const int tl = tid & 63;
    const int ph = tid >> 6;                   // p-quarter 0..3 (one wave each)
    const int t  = blockIdx.x * 64 + tl;       // t in [0, 32768)
    const float* p = ws + (size_t)ph * (NIG / 4) * SLICE + t;
    float s = 0.f;
#pragma unroll 8
    for (int i = 0; i < NIG / 4; ++i)          // 64 independent strided loads
        s += p[(size_t)i * SLICE];
    sh[tid] = s;
    __syncthreads();
    if (ph == 0) {
        s = sh[tl] + sh[64 + tl] + sh[128 + tl] + sh[192 + tl];
        float ss = s * s;
        ss += __shfl_xor(ss, 1);
        ss += __shfl_xor(ss, 2);
        ss += __shfl_xor(ss, 4);
        ss += __shfl_xor(ss, 8);
        ss += __shfl_xor(ss, 16);
        float n = sqrtf(ss);
        out[t] = s * n / (1.0f + ss);
    }
}

// ---------------- fallback (atomic path) if ws too small ----------------
__global__ __launch_bounds__(256, 2) void caps_main_atomic(const float* __restrict__ x,
                                                           const float* __restrict__ w,
                                                           float* __restrict__ out) {
    __shared__ float xsf[4 * C_ * 33];
    const int tid = threadIdx.x;
    const int i0 = blockIdx.x * 4;
    for (int k = tid; k < B_ * 4 * C_; k += 256) {
        int b = k >> 6, rem = k & 63;
        xsf[rem * 33 + b] = x[(size_t)b * (I_ * C_) + (size_t)i0 * C_ + rem];
    }
    __syncthreads();
    const int o = tid >> 3, u4 = (tid & 7) << 2;
    const float* wp = w + (size_t)i0 * (O_ * C_ * U_) + o * (C_ * U_) + u4;
    float4 acc[B_];
#pragma unroll
    for (int b = 0; b < B_; ++b) acc[b] = make_float4(0.f, 0.f, 0.f, 0.f);
    for (int il = 0; il < 4; ++il) {
        const float* wpi = wp + (size_t)il * (O_ * C_ * U_);
        const float* xr = &xsf[il * C_ * 33];
#pragma unroll
        for (int c = 0; c < C_; ++c) {
            float4 wv = *(const float4*)(wpi + c * U_);
            const float* xc = xr + c * 33;
#pragma unroll
            for (int b = 0; b < B_; ++b) {
                float xb = xc[b];
                acc[b].x = fmaf(xb, wv.x, acc[b].x);
                acc[b].y = fmaf(xb, wv.y, acc[b].y);
                acc[b].z = fmaf(xb, wv.z, acc[b].z);
                acc[b].w = fmaf(xb, wv.w, acc[b].w);
            }
        }
    }
    float* op = out + o * U_ + u4;
#pragma unroll
    for (int b = 0; b < B_; ++b) {
        float* p = op + (size_t)b * NCOL;
        atomicAdd(p + 0, acc[b].x);
        atomicAdd(p + 1, acc[b].y);
        atomicAdd(p + 2, acc[b].z);
        atomicAdd(p + 3, acc[b].w);
    }
}

__global__ void caps_squash_inplace(float* __restrict__ out) {
    int t = blockIdx.x * 256 + threadIdx.x;
    float s = out[t];
    float ss = s * s;
    ss += __shfl_xor(ss, 1);
    ss += __shfl_xor(ss, 2);
    ss += __shfl_xor(ss, 4);
    ss += __shfl_xor(ss, 8);
    ss += __shfl_xor(ss, 16);
    float n = sqrtf(ss);
    out[t] = s * n / (1.0f + ss);
}

extern "C" void kernel_launch(void* const* d_in, const int* in_sizes, int n_in,
                              void* d_out, int out_size, void* d_ws, size_t ws_size,
                              hipStream_t stream) {
    const float* x = (const float*)d_in[0];   // [B, I, C]
    const float* w = (const float*)d_in[1];   // [I, O, C, U]
    float* out = (float*)d_out;               // [B, O, 1, U] = 32768 floats

    const size_t need = (size_t)NIG * SLICE * sizeof(float);   // 32 MB
    if (ws_size >= need) {
        float* ws = (float*)d_ws;
        caps_partial<<<NIG * CQ, 256, 0, stream>>>(x, w, ws);
        caps_reduce_squash<<<SLICE / 64, 256, 0, stream>>>(ws, out);
    } else {
        hipMemsetAsync(out, 0, (size_t)SLICE * sizeof(float), stream);
        caps_main_atomic<<<I_ / 4, 256, 0, stream>>>(x, w, out);
        caps_squash_inplace<<<SLICE / 256, 256, 0, stream>>>(out);
    }
}